// Round 13
// baseline (1627.772 us; speedup 1.0000x reference)
//
#include <hip/hip_runtime.h>

// AttackLSTM R13 — 6-wave pipeline (R12 structure) + register-budget fix.
// R12 post-mortem: allocator chose 128 VGPRs (occupancy heuristic) while
// heavy waves have ~176 live -> weights parked in AGPRs, v_accvgpr_read per
// use in the step loop. R13: amdgpu_waves_per_eu(2,2) (true occupancy; budget
// 512/2=256) + in-loop VGPR pinning of each wave's weights so parking is
// useless. Pipeline, LDS layout, numerics unchanged (R12 passed, absmax 0).
//   w0: a0 rec   t=v    | w1: a1 ih-proj t=v-1 | w2: a1 rec t=v-2
//   w3: a2 proj  t=v-3  | w4: a2 rec     t=v-4 | w5: b0 dot + b-chain t=v-5

#define BB 256
#define TT 512

typedef _Float16 v2h __attribute__((ext_vector_type(2)));

__device__ __forceinline__ float sig_(float x) {
  return __builtin_amdgcn_rcpf(1.f + __builtin_amdgcn_exp2f(-1.44269504f * x));
}
__device__ __forceinline__ float tanh_(float x) {
  return __builtin_fmaf(2.f, __builtin_amdgcn_rcpf(1.f + __builtin_amdgcn_exp2f(-2.88539008f * x)), -1.f);
}

template <int K>
__device__ __forceinline__ float qb_(float v) {
  return __int_as_float(__builtin_amdgcn_update_dpp(
      0, __float_as_int(v), (K | (K << 2) | (K << 4) | (K << 6)), 0xF, 0xF, true));
}

__device__ __forceinline__ void ldsbar_() {
  asm volatile("s_waitcnt lgkmcnt(0)\n\ts_barrier" ::: "memory");
}

#if __has_builtin(__builtin_amdgcn_fdot2)
#define FDOT2(acc, a, b) (acc) = __builtin_amdgcn_fdot2((a), (b), (acc), false)
#else
#define FDOT2(acc, a, b) \
  (acc) = __builtin_fmaf((float)(a)[0], (float)(b)[0], \
          __builtin_fmaf((float)(a)[1], (float)(b)[1], (acc)))
#endif
#define KEEPP(a) asm volatile("" : "+v"(a))

// Pin 32 v2h regs (one weight row set) in VGPRs at this program point.
#define PIN32(w)                                                            \
  do {                                                                      \
    _Pragma("unroll") for (int _i = 0; _i < 32; ++_i) KEEPP((w)[_i]);       \
  } while (0)

__device__ __forceinline__ v2h bc2h_(int v) { return __builtin_bit_cast(v2h, v); }

// 64 halfs from LDS as 32 v2h via int4 reads (8x ds_read_b128).
__device__ __forceinline__ void load_h64(const _Float16* p, v2h hv[32]) {
  const int4* hp = reinterpret_cast<const int4*>(p);
#pragma unroll
  for (int i = 0; i < 8; ++i) {
    int4 blk = hp[i];
    hv[4 * i + 0] = bc2h_(blk.x);
    hv[4 * i + 1] = bc2h_(blk.y);
    hv[4 * i + 2] = bc2h_(blk.z);
    hv[4 * i + 3] = bc2h_(blk.w);
  }
}

// fp32 row of 64 -> 32 v2h.
__device__ __forceinline__ void load_row16(const float* src, v2h dst[32]) {
  const float4* p = reinterpret_cast<const float4*>(src);
#pragma unroll
  for (int i = 0; i < 16; ++i) {
    float4 v = p[i];
    dst[2 * i]     = v2h{(_Float16)v.x, (_Float16)v.y};
    dst[2 * i + 1] = v2h{(_Float16)v.z, (_Float16)v.w};
  }
}

__global__ __attribute__((amdgpu_flat_work_group_size(384, 384),
                          amdgpu_waves_per_eu(2, 2)))
void lstm_pipe_k(
    const float* __restrict__ x,
    const float* __restrict__ wih_a0, const float* __restrict__ whh_a0,
    const float* __restrict__ bih_a0, const float* __restrict__ bhh_a0,
    const float* __restrict__ wih_a1, const float* __restrict__ whh_a1,
    const float* __restrict__ bih_a1, const float* __restrict__ bhh_a1,
    const float* __restrict__ wih_a2, const float* __restrict__ whh_a2,
    const float* __restrict__ bih_a2, const float* __restrict__ bhh_a2,
    const float* __restrict__ wih_b0, const float* __restrict__ whh_b0,
    const float* __restrict__ bih_b0, const float* __restrict__ bhh_b0,
    const float* __restrict__ wih_b1, const float* __restrict__ whh_b1,
    const float* __restrict__ bih_b1, const float* __restrict__ bhh_b1,
    const float* __restrict__ wih_b2, const float* __restrict__ whh_b2,
    const float* __restrict__ bih_b2, const float* __restrict__ bhh_b2,
    float* __restrict__ out)  // [B,T]
{
  const int b = blockIdx.x;
  const int tid = threadIdx.x;
  const int wave = tid >> 6;
  const int lane = tid & 63;

  __shared__ _Float16 hh[3 * 2 * 64];   // [layer][slot][hid]
  __shared__ float pj[2 * 2 * 64 * 4];  // [proj][slot][hid][gate]
  __shared__ float xs[TT];

  for (int i = tid; i < TT; i += 384) xs[i] = x[(size_t)b * TT + i];
  if (tid < 192) reinterpret_cast<int*>(hh)[tid] = 0;

  v2h wt[4][32];
  float bias[4] = {0.f, 0.f, 0.f, 0.f};
  float wi0_[4] = {0.f, 0.f, 0.f, 0.f};
  float whb0[4] = {}, wi1b[4] = {}, wh1b[4] = {}, bb1[4] = {},
        wi2b[4] = {}, wh2b[4] = {}, bb2[4] = {};

  if (wave == 0) {
#pragma unroll
    for (int q = 0; q < 4; ++q) {
      const int row = q * 64 + lane;
      load_row16(whh_a0 + row * 64, wt[q]);
      bias[q] = bih_a0[row] + bhh_a0[row];
      wi0_[q] = wih_a0[row];
    }
    PIN32(wt[0]); PIN32(wt[1]); PIN32(wt[2]); PIN32(wt[3]);
  } else if (wave == 1) {
#pragma unroll
    for (int q = 0; q < 4; ++q) load_row16(wih_a1 + (q * 64 + lane) * 64, wt[q]);
    PIN32(wt[0]); PIN32(wt[1]); PIN32(wt[2]); PIN32(wt[3]);
  } else if (wave == 2) {
#pragma unroll
    for (int q = 0; q < 4; ++q) {
      const int row = q * 64 + lane;
      load_row16(whh_a1 + row * 64, wt[q]);
      bias[q] = bih_a1[row] + bhh_a1[row];
    }
    PIN32(wt[0]); PIN32(wt[1]); PIN32(wt[2]); PIN32(wt[3]);
  } else if (wave == 3) {
#pragma unroll
    for (int q = 0; q < 4; ++q) load_row16(wih_a2 + (q * 64 + lane) * 64, wt[q]);
    PIN32(wt[0]); PIN32(wt[1]); PIN32(wt[2]); PIN32(wt[3]);
  } else if (wave == 4) {
#pragma unroll
    for (int q = 0; q < 4; ++q) {
      const int row = q * 64 + lane;
      load_row16(whh_a2 + row * 64, wt[q]);
      bias[q] = bih_a2[row] + bhh_a2[row];
    }
    PIN32(wt[0]); PIN32(wt[1]); PIN32(wt[2]); PIN32(wt[3]);
  } else {
    const int q = lane & 3;
    load_row16(wih_b0 + q * 64, wt[0]);
    bias[0] = bih_b0[q] + bhh_b0[q];
#pragma unroll
    for (int k = 0; k < 4; ++k) {
      whb0[k] = whh_b0[k];
      wi1b[k] = wih_b1[k]; wh1b[k] = whh_b1[k]; bb1[k] = bih_b1[k] + bhh_b1[k];
      wi2b[k] = wih_b2[k]; wh2b[k] = whh_b2[k]; bb2[k] = bih_b2[k] + bhh_b2[k];
    }
    PIN32(wt[0]);
  }
  __syncthreads();

  float c = 0.f;
  float h0b = 0.f, c0b = 0.f, h1b = 0.f, c1b = 0.f, h2b = 0.f, c2b = 0.f;

  for (int v = 0; v < TT + 5; ++v) {
    if (wave == 0) {
      const int t = v;
      if (t < TT) {
        PIN32(wt[0]); PIN32(wt[1]); PIN32(wt[2]); PIN32(wt[3]);
        v2h hv[32];
        load_h64(hh + 0 * 128 + ((t + 1) & 1) * 64, hv);
        const float xv = xs[t];
        float p0 = __builtin_fmaf(wi0_[0], xv, bias[0]);
        float p1 = __builtin_fmaf(wi0_[1], xv, bias[1]);
        float p2 = __builtin_fmaf(wi0_[2], xv, bias[2]);
        float p3 = __builtin_fmaf(wi0_[3], xv, bias[3]);
#pragma unroll
        for (int j = 0; j < 32; ++j) {
          FDOT2(p0, wt[0][j], hv[j]); FDOT2(p1, wt[1][j], hv[j]);
          FDOT2(p2, wt[2][j], hv[j]); FDOT2(p3, wt[3][j], hv[j]);
        }
        float gi = sig_(p0), gf = sig_(p1), gg = tanh_(p2), go = sig_(p3);
        c = __builtin_fmaf(gf, c, gi * gg);
        hh[0 * 128 + (t & 1) * 64 + lane] = (_Float16)(go * tanh_(c));
      }
    } else if (wave == 1) {
      const int t = v - 1;
      if (t >= 0 && t < TT) {
        PIN32(wt[0]); PIN32(wt[1]); PIN32(wt[2]); PIN32(wt[3]);
        v2h hv[32];
        load_h64(hh + 0 * 128 + (t & 1) * 64, hv);
        float p0 = 0.f, p1 = 0.f, p2 = 0.f, p3 = 0.f;
#pragma unroll
        for (int j = 0; j < 32; ++j) {
          FDOT2(p0, wt[0][j], hv[j]); FDOT2(p1, wt[1][j], hv[j]);
          FDOT2(p2, wt[2][j], hv[j]); FDOT2(p3, wt[3][j], hv[j]);
        }
        *reinterpret_cast<float4*>(&pj[(0 * 2 + (t & 1)) * 256 + lane * 4]) =
            float4{p0, p1, p2, p3};
      }
    } else if (wave == 2) {
      const int t = v - 2;
      if (t >= 0 && t < TT) {
        PIN32(wt[0]); PIN32(wt[1]); PIN32(wt[2]); PIN32(wt[3]);
        v2h hv[32];
        load_h64(hh + 1 * 128 + ((t + 1) & 1) * 64, hv);
        float4 pr = *reinterpret_cast<const float4*>(
            &pj[(0 * 2 + (t & 1)) * 256 + lane * 4]);
        float p0 = bias[0] + pr.x, p1 = bias[1] + pr.y;
        float p2 = bias[2] + pr.z, p3 = bias[3] + pr.w;
#pragma unroll
        for (int j = 0; j < 32; ++j) {
          FDOT2(p0, wt[0][j], hv[j]); FDOT2(p1, wt[1][j], hv[j]);
          FDOT2(p2, wt[2][j], hv[j]); FDOT2(p3, wt[3][j], hv[j]);
        }
        float gi = sig_(p0), gf = sig_(p1), gg = tanh_(p2), go = sig_(p3);
        c = __builtin_fmaf(gf, c, gi * gg);
        hh[1 * 128 + (t & 1) * 64 + lane] = (_Float16)(go * tanh_(c));
      }
    } else if (wave == 3) {
      const int t = v - 3;
      if (t >= 0 && t < TT) {
        PIN32(wt[0]); PIN32(wt[1]); PIN32(wt[2]); PIN32(wt[3]);
        v2h hv[32];
        load_h64(hh + 1 * 128 + (t & 1) * 64, hv);
        float p0 = 0.f, p1 = 0.f, p2 = 0.f, p3 = 0.f;
#pragma unroll
        for (int j = 0; j < 32; ++j) {
          FDOT2(p0, wt[0][j], hv[j]); FDOT2(p1, wt[1][j], hv[j]);
          FDOT2(p2, wt[2][j], hv[j]); FDOT2(p3, wt[3][j], hv[j]);
        }
        *reinterpret_cast<float4*>(&pj[(1 * 2 + (t & 1)) * 256 + lane * 4]) =
            float4{p0, p1, p2, p3};
      }
    } else if (wave == 4) {
      const int t = v - 4;
      if (t >= 0 && t < TT) {
        PIN32(wt[0]); PIN32(wt[1]); PIN32(wt[2]); PIN32(wt[3]);
        v2h hv[32];
        load_h64(hh + 2 * 128 + ((t + 1) & 1) * 64, hv);
        float4 pr = *reinterpret_cast<const float4*>(
            &pj[(1 * 2 + (t & 1)) * 256 + lane * 4]);
        float p0 = bias[0] + pr.x, p1 = bias[1] + pr.y;
        float p2 = bias[2] + pr.z, p3 = bias[3] + pr.w;
#pragma unroll
        for (int j = 0; j < 32; ++j) {
          FDOT2(p0, wt[0][j], hv[j]); FDOT2(p1, wt[1][j], hv[j]);
          FDOT2(p2, wt[2][j], hv[j]); FDOT2(p3, wt[3][j], hv[j]);
        }
        float gi = sig_(p0), gf = sig_(p1), gg = tanh_(p2), go = sig_(p3);
        c = __builtin_fmaf(gf, c, gi * gg);
        hh[2 * 128 + (t & 1) * 64 + lane] = (_Float16)(go * tanh_(c));
      }
    } else {
      const int t = v - 5;
      if (t >= 0 && t < TT) {
        PIN32(wt[0]);
        v2h hv[32];
        load_h64(hh + 2 * 128 + (t & 1) * 64, hv);
        float pg = bias[0];
#pragma unroll
        for (int j = 0; j < 32; ++j) FDOT2(pg, wt[0][j], hv[j]);
        float p_i = qb_<0>(pg), p_f = qb_<1>(pg), p_g = qb_<2>(pg), p_o = qb_<3>(pg);
        float i0 = sig_(__builtin_fmaf(whb0[0], h0b, p_i));
        float f0 = sig_(__builtin_fmaf(whb0[1], h0b, p_f));
        float g0 = tanh_(__builtin_fmaf(whb0[2], h0b, p_g));
        float o0 = sig_(__builtin_fmaf(whb0[3], h0b, p_o));
        c0b = __builtin_fmaf(f0, c0b, i0 * g0);
        h0b = o0 * tanh_(c0b);
        float i1 = sig_(bb1[0] + __builtin_fmaf(wi1b[0], h0b, wh1b[0] * h1b));
        float f1 = sig_(bb1[1] + __builtin_fmaf(wi1b[1], h0b, wh1b[1] * h1b));
        float g1 = tanh_(bb1[2] + __builtin_fmaf(wi1b[2], h0b, wh1b[2] * h1b));
        float o1 = sig_(bb1[3] + __builtin_fmaf(wi1b[3], h0b, wh1b[3] * h1b));
        c1b = __builtin_fmaf(f1, c1b, i1 * g1);
        h1b = o1 * tanh_(c1b);
        float i2 = sig_(bb2[0] + __builtin_fmaf(wi2b[0], h1b, wh2b[0] * h2b));
        float f2 = sig_(bb2[1] + __builtin_fmaf(wi2b[1], h1b, wh2b[1] * h2b));
        float g2 = tanh_(bb2[2] + __builtin_fmaf(wi2b[2], h1b, wh2b[2] * h2b));
        float o2 = sig_(bb2[3] + __builtin_fmaf(wi2b[3], h1b, wh2b[3] * h2b));
        c2b = __builtin_fmaf(f2, c2b, i2 * g2);
        h2b = o2 * tanh_(c2b);
        if (lane == 0) out[(size_t)b * TT + t] = h2b;
      }
    }
    ldsbar_();
  }
}

extern "C" void kernel_launch(void* const* d_in, const int* in_sizes, int n_in,
                              void* d_out, int out_size, void* d_ws, size_t ws_size,
                              hipStream_t stream) {
  const float* x      = (const float*)d_in[0];
  const float* wih_a0 = (const float*)d_in[1];
  const float* whh_a0 = (const float*)d_in[2];
  const float* bih_a0 = (const float*)d_in[3];
  const float* bhh_a0 = (const float*)d_in[4];
  const float* wih_a1 = (const float*)d_in[5];
  const float* whh_a1 = (const float*)d_in[6];
  const float* bih_a1 = (const float*)d_in[7];
  const float* bhh_a1 = (const float*)d_in[8];
  const float* wih_a2 = (const float*)d_in[9];
  const float* whh_a2 = (const float*)d_in[10];
  const float* bih_a2 = (const float*)d_in[11];
  const float* bhh_a2 = (const float*)d_in[12];
  const float* wih_b0 = (const float*)d_in[13];
  const float* whh_b0 = (const float*)d_in[14];
  const float* bih_b0 = (const float*)d_in[15];
  const float* bhh_b0 = (const float*)d_in[16];
  const float* wih_b1 = (const float*)d_in[17];
  const float* whh_b1 = (const float*)d_in[18];
  const float* bih_b1 = (const float*)d_in[19];
  const float* bhh_b1 = (const float*)d_in[20];
  const float* wih_b2 = (const float*)d_in[21];
  const float* whh_b2 = (const float*)d_in[22];
  const float* bih_b2 = (const float*)d_in[23];
  const float* bhh_b2 = (const float*)d_in[24];
  float* out = (float*)d_out;

  lstm_pipe_k<<<BB, 384, 0, stream>>>(
      x,
      wih_a0, whh_a0, bih_a0, bhh_a0,
      wih_a1, whh_a1, bih_a1, bhh_a1,
      wih_a2, whh_a2, bih_a2, bhh_a2,
      wih_b0, whh_b0, bih_b0, bhh_b0,
      wih_b1, whh_b1, bih_b1, bhh_b1,
      wih_b2, whh_b2, bih_b2, bhh_b2,
      out);
}

// Round 15
// 529.825 us; speedup vs baseline: 3.0723x; 3.0723x over previous
//
#include <hip/hip_runtime.h>

// AttackLSTM R15 — R12's 6-wave pipeline + forced 192 arch-VGPR allocation.
// R14 taught: v_dot2_f32_f16 (VOP3P) cannot source AGPRs -> R12's AGPR-parked
// weights pay v_accvgpr_read per use. R13 taught: squeezing into 128 arch
// spills to scratch. R15: clobber v191 at entry -> VGPR usage 192 (legal at
// waves_per_eu(1,2); 2x192=384 <= 512/SIMD so 2 waves/SIMD still fits).
// Heavy-wave pressure ~175 < 192 -> weights stay in arch VGPRs, no copies.
//   w0: a0 rec t=v | w1: a1 proj t=v-1 | w2: a1 rec t=v-2
//   w3: a2 proj t=v-3 | w4: a2 rec t=v-4 | w5: b0 dot + b-chain t=v-5

#define BB 256
#define TT 512

typedef _Float16 v2h __attribute__((ext_vector_type(2)));

__device__ __forceinline__ float sig_(float x) {
  return __builtin_amdgcn_rcpf(1.f + __builtin_amdgcn_exp2f(-1.44269504f * x));
}
__device__ __forceinline__ float tanh_(float x) {
  return __builtin_fmaf(2.f, __builtin_amdgcn_rcpf(1.f + __builtin_amdgcn_exp2f(-2.88539008f * x)), -1.f);
}

template <int K>
__device__ __forceinline__ float qb_(float v) {
  return __int_as_float(__builtin_amdgcn_update_dpp(
      0, __float_as_int(v), (K | (K << 2) | (K << 4) | (K << 6)), 0xF, 0xF, true));
}

__device__ __forceinline__ void ldsbar_() {
  asm volatile("s_waitcnt lgkmcnt(0)\n\ts_barrier" ::: "memory");
}

#if __has_builtin(__builtin_amdgcn_fdot2)
#define FDOT2(acc, a, b) (acc) = __builtin_amdgcn_fdot2((a), (b), (acc), false)
#else
#define FDOT2(acc, a, b) \
  (acc) = __builtin_fmaf((float)(a)[0], (float)(b)[0], \
          __builtin_fmaf((float)(a)[1], (float)(b)[1], (acc)))
#endif
#define KEEPP(a) asm volatile("" : "+v"(a))
#define PIN32(w)                                                            \
  do {                                                                      \
    _Pragma("unroll") for (int _i = 0; _i < 32; ++_i) KEEPP((w)[_i]);       \
  } while (0)

__device__ __forceinline__ v2h bc2h_(int v) { return __builtin_bit_cast(v2h, v); }

// 64 halfs from LDS as 32 v2h via int4 reads (8x ds_read_b128).
__device__ __forceinline__ void load_h64(const _Float16* p, v2h hv[32]) {
  const int4* hp = reinterpret_cast<const int4*>(p);
#pragma unroll
  for (int i = 0; i < 8; ++i) {
    int4 blk = hp[i];
    hv[4 * i + 0] = bc2h_(blk.x);
    hv[4 * i + 1] = bc2h_(blk.y);
    hv[4 * i + 2] = bc2h_(blk.z);
    hv[4 * i + 3] = bc2h_(blk.w);
  }
}

// fp32 row of 64 -> 32 v2h.
__device__ __forceinline__ void load_row16(const float* src, v2h dst[32]) {
  const float4* p = reinterpret_cast<const float4*>(src);
#pragma unroll
  for (int i = 0; i < 16; ++i) {
    float4 v = p[i];
    dst[2 * i]     = v2h{(_Float16)v.x, (_Float16)v.y};
    dst[2 * i + 1] = v2h{(_Float16)v.z, (_Float16)v.w};
  }
}

__global__ __attribute__((amdgpu_flat_work_group_size(384, 384),
                          amdgpu_waves_per_eu(1, 2)))
void lstm_pipe_k(
    const float* __restrict__ x,
    const float* __restrict__ wih_a0, const float* __restrict__ whh_a0,
    const float* __restrict__ bih_a0, const float* __restrict__ bhh_a0,
    const float* __restrict__ wih_a1, const float* __restrict__ whh_a1,
    const float* __restrict__ bih_a1, const float* __restrict__ bhh_a1,
    const float* __restrict__ wih_a2, const float* __restrict__ whh_a2,
    const float* __restrict__ bih_a2, const float* __restrict__ bhh_a2,
    const float* __restrict__ wih_b0, const float* __restrict__ whh_b0,
    const float* __restrict__ bih_b0, const float* __restrict__ bhh_b0,
    const float* __restrict__ wih_b1, const float* __restrict__ whh_b1,
    const float* __restrict__ bih_b1, const float* __restrict__ bhh_b1,
    const float* __restrict__ wih_b2, const float* __restrict__ whh_b2,
    const float* __restrict__ bih_b2, const float* __restrict__ bhh_b2,
    float* __restrict__ out)  // [B,T]
{
  // Force arch-VGPR allocation to 192 (see header comment).
  asm volatile("" ::: "v190", "v191");

  const int b = blockIdx.x;
  const int tid = threadIdx.x;
  const int wave = tid >> 6;
  const int lane = tid & 63;

  __shared__ _Float16 hh[3 * 2 * 64];   // [layer][slot][hid]
  __shared__ float pj[2 * 2 * 64 * 4];  // [proj][slot][hid][gate]
  __shared__ float xs[TT];

  for (int i = tid; i < TT; i += 384) xs[i] = x[(size_t)b * TT + i];
  if (tid < 192) reinterpret_cast<int*>(hh)[tid] = 0;

  v2h wt[4][32];
  float bias[4] = {0.f, 0.f, 0.f, 0.f};
  float wi0_[4] = {0.f, 0.f, 0.f, 0.f};
  float whb0[4] = {}, wi1b[4] = {}, wh1b[4] = {}, bb1[4] = {},
        wi2b[4] = {}, wh2b[4] = {}, bb2[4] = {};

  if (wave == 0) {
#pragma unroll
    for (int q = 0; q < 4; ++q) {
      const int row = q * 64 + lane;
      load_row16(whh_a0 + row * 64, wt[q]);
      bias[q] = bih_a0[row] + bhh_a0[row];
      wi0_[q] = wih_a0[row];
    }
    PIN32(wt[0]); PIN32(wt[1]); PIN32(wt[2]); PIN32(wt[3]);
  } else if (wave == 1) {
#pragma unroll
    for (int q = 0; q < 4; ++q) load_row16(wih_a1 + (q * 64 + lane) * 64, wt[q]);
    PIN32(wt[0]); PIN32(wt[1]); PIN32(wt[2]); PIN32(wt[3]);
  } else if (wave == 2) {
#pragma unroll
    for (int q = 0; q < 4; ++q) {
      const int row = q * 64 + lane;
      load_row16(whh_a1 + row * 64, wt[q]);
      bias[q] = bih_a1[row] + bhh_a1[row];
    }
    PIN32(wt[0]); PIN32(wt[1]); PIN32(wt[2]); PIN32(wt[3]);
  } else if (wave == 3) {
#pragma unroll
    for (int q = 0; q < 4; ++q) load_row16(wih_a2 + (q * 64 + lane) * 64, wt[q]);
    PIN32(wt[0]); PIN32(wt[1]); PIN32(wt[2]); PIN32(wt[3]);
  } else if (wave == 4) {
#pragma unroll
    for (int q = 0; q < 4; ++q) {
      const int row = q * 64 + lane;
      load_row16(whh_a2 + row * 64, wt[q]);
      bias[q] = bih_a2[row] + bhh_a2[row];
    }
    PIN32(wt[0]); PIN32(wt[1]); PIN32(wt[2]); PIN32(wt[3]);
  } else {
    const int q = lane & 3;
    load_row16(wih_b0 + q * 64, wt[0]);
    bias[0] = bih_b0[q] + bhh_b0[q];
#pragma unroll
    for (int k = 0; k < 4; ++k) {
      whb0[k] = whh_b0[k];
      wi1b[k] = wih_b1[k]; wh1b[k] = whh_b1[k]; bb1[k] = bih_b1[k] + bhh_b1[k];
      wi2b[k] = wih_b2[k]; wh2b[k] = whh_b2[k]; bb2[k] = bih_b2[k] + bhh_b2[k];
    }
    PIN32(wt[0]);
  }
  __syncthreads();

  float c = 0.f;
  float h0b = 0.f, c0b = 0.f, h1b = 0.f, c1b = 0.f, h2b = 0.f, c2b = 0.f;

  for (int v = 0; v < TT + 5; ++v) {
    if (wave == 0) {
      const int t = v;
      if (t < TT) {
        v2h hv[32];
        load_h64(hh + 0 * 128 + ((t + 1) & 1) * 64, hv);
        const float xv = xs[t];
        float p0 = __builtin_fmaf(wi0_[0], xv, bias[0]);
        float p1 = __builtin_fmaf(wi0_[1], xv, bias[1]);
        float p2 = __builtin_fmaf(wi0_[2], xv, bias[2]);
        float p3 = __builtin_fmaf(wi0_[3], xv, bias[3]);
#pragma unroll
        for (int j = 0; j < 32; ++j) {
          FDOT2(p0, wt[0][j], hv[j]); FDOT2(p1, wt[1][j], hv[j]);
          FDOT2(p2, wt[2][j], hv[j]); FDOT2(p3, wt[3][j], hv[j]);
        }
        float gi = sig_(p0), gf = sig_(p1), gg = tanh_(p2), go = sig_(p3);
        c = __builtin_fmaf(gf, c, gi * gg);
        hh[0 * 128 + (t & 1) * 64 + lane] = (_Float16)(go * tanh_(c));
      }
    } else if (wave == 1) {
      const int t = v - 1;
      if (t >= 0 && t < TT) {
        v2h hv[32];
        load_h64(hh + 0 * 128 + (t & 1) * 64, hv);
        float p0 = 0.f, p1 = 0.f, p2 = 0.f, p3 = 0.f;
#pragma unroll
        for (int j = 0; j < 32; ++j) {
          FDOT2(p0, wt[0][j], hv[j]); FDOT2(p1, wt[1][j], hv[j]);
          FDOT2(p2, wt[2][j], hv[j]); FDOT2(p3, wt[3][j], hv[j]);
        }
        *reinterpret_cast<float4*>(&pj[(0 * 2 + (t & 1)) * 256 + lane * 4]) =
            float4{p0, p1, p2, p3};
      }
    } else if (wave == 2) {
      const int t = v - 2;
      if (t >= 0 && t < TT) {
        v2h hv[32];
        load_h64(hh + 1 * 128 + ((t + 1) & 1) * 64, hv);
        float4 pr = *reinterpret_cast<const float4*>(
            &pj[(0 * 2 + (t & 1)) * 256 + lane * 4]);
        float p0 = bias[0] + pr.x, p1 = bias[1] + pr.y;
        float p2 = bias[2] + pr.z, p3 = bias[3] + pr.w;
#pragma unroll
        for (int j = 0; j < 32; ++j) {
          FDOT2(p0, wt[0][j], hv[j]); FDOT2(p1, wt[1][j], hv[j]);
          FDOT2(p2, wt[2][j], hv[j]); FDOT2(p3, wt[3][j], hv[j]);
        }
        float gi = sig_(p0), gf = sig_(p1), gg = tanh_(p2), go = sig_(p3);
        c = __builtin_fmaf(gf, c, gi * gg);
        hh[1 * 128 + (t & 1) * 64 + lane] = (_Float16)(go * tanh_(c));
      }
    } else if (wave == 3) {
      const int t = v - 3;
      if (t >= 0 && t < TT) {
        v2h hv[32];
        load_h64(hh + 1 * 128 + (t & 1) * 64, hv);
        float p0 = 0.f, p1 = 0.f, p2 = 0.f, p3 = 0.f;
#pragma unroll
        for (int j = 0; j < 32; ++j) {
          FDOT2(p0, wt[0][j], hv[j]); FDOT2(p1, wt[1][j], hv[j]);
          FDOT2(p2, wt[2][j], hv[j]); FDOT2(p3, wt[3][j], hv[j]);
        }
        *reinterpret_cast<float4*>(&pj[(1 * 2 + (t & 1)) * 256 + lane * 4]) =
            float4{p0, p1, p2, p3};
      }
    } else if (wave == 4) {
      const int t = v - 4;
      if (t >= 0 && t < TT) {
        v2h hv[32];
        load_h64(hh + 2 * 128 + ((t + 1) & 1) * 64, hv);
        float4 pr = *reinterpret_cast<const float4*>(
            &pj[(1 * 2 + (t & 1)) * 256 + lane * 4]);
        float p0 = bias[0] + pr.x, p1 = bias[1] + pr.y;
        float p2 = bias[2] + pr.z, p3 = bias[3] + pr.w;
#pragma unroll
        for (int j = 0; j < 32; ++j) {
          FDOT2(p0, wt[0][j], hv[j]); FDOT2(p1, wt[1][j], hv[j]);
          FDOT2(p2, wt[2][j], hv[j]); FDOT2(p3, wt[3][j], hv[j]);
        }
        float gi = sig_(p0), gf = sig_(p1), gg = tanh_(p2), go = sig_(p3);
        c = __builtin_fmaf(gf, c, gi * gg);
        hh[2 * 128 + (t & 1) * 64 + lane] = (_Float16)(go * tanh_(c));
      }
    } else {
      const int t = v - 5;
      if (t >= 0 && t < TT) {
        v2h hv[32];
        load_h64(hh + 2 * 128 + (t & 1) * 64, hv);
        float pg = bias[0];
#pragma unroll
        for (int j = 0; j < 32; ++j) FDOT2(pg, wt[0][j], hv[j]);
        float p_i = qb_<0>(pg), p_f = qb_<1>(pg), p_g = qb_<2>(pg), p_o = qb_<3>(pg);
        float i0 = sig_(__builtin_fmaf(whb0[0], h0b, p_i));
        float f0 = sig_(__builtin_fmaf(whb0[1], h0b, p_f));
        float g0 = tanh_(__builtin_fmaf(whb0[2], h0b, p_g));
        float o0 = sig_(__builtin_fmaf(whb0[3], h0b, p_o));
        c0b = __builtin_fmaf(f0, c0b, i0 * g0);
        h0b = o0 * tanh_(c0b);
        float i1 = sig_(bb1[0] + __builtin_fmaf(wi1b[0], h0b, wh1b[0] * h1b));
        float f1 = sig_(bb1[1] + __builtin_fmaf(wi1b[1], h0b, wh1b[1] * h1b));
        float g1 = tanh_(bb1[2] + __builtin_fmaf(wi1b[2], h0b, wh1b[2] * h1b));
        float o1 = sig_(bb1[3] + __builtin_fmaf(wi1b[3], h0b, wh1b[3] * h1b));
        c1b = __builtin_fmaf(f1, c1b, i1 * g1);
        h1b = o1 * tanh_(c1b);
        float i2 = sig_(bb2[0] + __builtin_fmaf(wi2b[0], h1b, wh2b[0] * h2b));
        float f2 = sig_(bb2[1] + __builtin_fmaf(wi2b[1], h1b, wh2b[1] * h2b));
        float g2 = tanh_(bb2[2] + __builtin_fmaf(wi2b[2], h1b, wh2b[2] * h2b));
        float o2 = sig_(bb2[3] + __builtin_fmaf(wi2b[3], h1b, wh2b[3] * h2b));
        c2b = __builtin_fmaf(f2, c2b, i2 * g2);
        h2b = o2 * tanh_(c2b);
        if (lane == 0) out[(size_t)b * TT + t] = h2b;
      }
    }
    ldsbar_();
  }
}

extern "C" void kernel_launch(void* const* d_in, const int* in_sizes, int n_in,
                              void* d_out, int out_size, void* d_ws, size_t ws_size,
                              hipStream_t stream) {
  const float* x      = (const float*)d_in[0];
  const float* wih_a0 = (const float*)d_in[1];
  const float* whh_a0 = (const float*)d_in[2];
  const float* bih_a0 = (const float*)d_in[3];
  const float* bhh_a0 = (const float*)d_in[4];
  const float* wih_a1 = (const float*)d_in[5];
  const float* whh_a1 = (const float*)d_in[6];
  const float* bih_a1 = (const float*)d_in[7];
  const float* bhh_a1 = (const float*)d_in[8];
  const float* wih_a2 = (const float*)d_in[9];
  const float* whh_a2 = (const float*)d_in[10];
  const float* bih_a2 = (const float*)d_in[11];
  const float* bhh_a2 = (const float*)d_in[12];
  const float* wih_b0 = (const float*)d_in[13];
  const float* whh_b0 = (const float*)d_in[14];
  const float* bih_b0 = (const float*)d_in[15];
  const float* bhh_b0 = (const float*)d_in[16];
  const float* wih_b1 = (const float*)d_in[17];
  const float* whh_b1 = (const float*)d_in[18];
  const float* bih_b1 = (const float*)d_in[19];
  const float* bhh_b1 = (const float*)d_in[20];
  const float* wih_b2 = (const float*)d_in[21];
  const float* whh_b2 = (const float*)d_in[22];
  const float* bih_b2 = (const float*)d_in[23];
  const float* bhh_b2 = (const float*)d_in[24];
  float* out = (float*)d_out;

  lstm_pipe_k<<<BB, 384, 0, stream>>>(
      x,
      wih_a0, whh_a0, bih_a0, bhh_a0,
      wih_a1, whh_a1, bih_a1, bhh_a1,
      wih_a2, whh_a2, bih_a2, bhh_a2,
      wih_b0, whh_b0, bih_b0, bhh_b0,
      wih_b1, whh_b1, bih_b1, bhh_b1,
      wih_b2, whh_b2, bih_b2, bhh_b2,
      out);
}